// Round 8
// baseline (431.765 us; speedup 1.0000x reference)
//
#include <hip/hip_runtime.h>

// Soft-DTW, B=64, L=1024, C=64, gamma=1.
// R2 skeleton: 16 row-bands of 64 rows per batch; wave = band; lane = row.
// 4 waves/block, 4 blocks/batch (256 blocks = 256 CUs, 1 wave/SIMD).
// R8 changes vs R2 (math identical, 3-exp softmin in base-2 log domain):
//  1) FINE-GRAINED band handoff: producer publishes a bottom-row column
//     counter (LDS, release) every 16 steps; consumer waits per-8-col group
//     and loads 8 top-row values/group. Band lag 128 -> ~80 steps.
//  2) gram(t+1) INTERLEAVED into dp_chunk(t): 2 MFMA-pairs per 8-step group,
//     fully unrolled (compile-time indices), rides in the exp2/log2 stall
//     shadow instead of serializing after the chunk.
// Cross-block boundaries (bands 3->4, 7->8, 11->12): global HX + agent flag,
// chunk-granular (lag 2) as before.

typedef unsigned short ushort_t;
typedef __attribute__((ext_vector_type(8))) short short8;
typedef __attribute__((ext_vector_type(4))) float f32x4;
typedef __attribute__((ext_vector_type(4))) unsigned short ushort4v;

constexpr int B_ = 64, L_ = 1024, C_ = 64;
constexpr int DSTR = 130;    // u16 row stride (65 dwords), 2-way banks max
constexpr int HBSTR = 1280;  // Hb row stride: pads LDS > 80KiB -> 1 block/CU

#define BIGV 1e10f
#define INV_LN2 1.44269504088896340736f
#define LN2F 0.69314718055994530942f

template<int N> struct IC { static constexpr int v = N; };
template<int I, int N, class F>
static __device__ __forceinline__ void sfor(F&& f) {
  if constexpr (I < N) { f(IC<I>{}); sfor<I + 1, N>(f); }
}

static __device__ __forceinline__ ushort_t f2bf(float f) {
  unsigned u = __builtin_bit_cast(unsigned, f);
  unsigned r = (u + 0x7fffu + ((u >> 16) & 1u)) >> 16;
  return (ushort_t)r;
}
static __device__ __forceinline__ unsigned cvt_pk_bf16(float lo, float hi) {
  unsigned r; asm("v_cvt_pk_bf16_f32 %0, %1, %2" : "=v"(r) : "v"(lo), "v"(hi)); return r;
}
// lane i <- lane i-1; lane 0 <- old[0]   (wave_shr:1)
static __device__ __forceinline__ float dpp_shr1(float old, float src) {
  return __builtin_bit_cast(float, __builtin_amdgcn_update_dpp(
      __builtin_bit_cast(int, old), __builtin_bit_cast(int, src), 0x138, 0xF, 0xF, false));
}
// lane i <- lane i+1 (wave_shl:1, lane 63 keeps old)
static __device__ __forceinline__ float dpp_shl1(float v) {
  return __builtin_bit_cast(float, __builtin_amdgcn_update_dpp(
      __builtin_bit_cast(int, v), __builtin_bit_cast(int, v), 0x130, 0xF, 0xF, false));
}

// Pass 1: bf16 conversion (RNE), squared norms pre-scaled by 1/ln2, zero flags.
__global__ __launch_bounds__(256) void prep_kernel(
    const float* __restrict__ x, const float* __restrict__ y,
    ushort_t* __restrict__ xb, ushort_t* __restrict__ yb,
    float* __restrict__ x2, float* __restrict__ y2, int* __restrict__ flagsG)
{
  if (blockIdx.x == 0 && threadIdx.x < 192) flagsG[threadIdx.x] = 0;
  const int lane = threadIdx.x & 63;
  const int sub = lane >> 4;
  const int cg  = lane & 15;
  const int wv = (blockIdx.x * blockDim.x + threadIdx.x) >> 6;
  const int nw = (gridDim.x * blockDim.x) >> 6;
  const int totalGroups = (2 * B_ * L_) >> 2;
  for (int g = wv; g < totalGroups; g += nw) {
    int r = g * 4 + sub;
    const float* src; ushort_t* dst; float* nrm;
    if (r < B_ * L_) { src = x; dst = xb; nrm = x2; }
    else             { r -= B_ * L_; src = y; dst = yb; nrm = y2; }
    const float4 v = *(const float4*)(src + (size_t)r * C_ + cg * 4);
    ushort4v p;
    p.x = f2bf(v.x); p.y = f2bf(v.y); p.z = f2bf(v.z); p.w = f2bf(v.w);
    *(ushort4v*)(dst + (size_t)r * C_ + cg * 4) = p;
    float s = v.x*v.x + v.y*v.y + v.z*v.z + v.w*v.w;
    s += __shfl_xor(s, 1); s += __shfl_xor(s, 2);
    s += __shfl_xor(s, 4); s += __shfl_xor(s, 8);
    if (cg == 0) nrm[r] = s * INV_LN2;
  }
}

static __device__ __forceinline__ void spin_lds(int* f, int v) {
  int k = 0;
  while (__hip_atomic_load(f, __ATOMIC_ACQUIRE, __HIP_MEMORY_SCOPE_WORKGROUP) < v) {
    __builtin_amdgcn_s_sleep(1);
    if (++k > (1 << 26)) break;
  }
}
static __device__ __forceinline__ void spin_glb(int* f, int v) {
  int k = 0;
  while (__hip_atomic_load(f, __ATOMIC_ACQUIRE, __HIP_MEMORY_SCOPE_AGENT) < v) {
    __builtin_amdgcn_s_sleep(2);
    if (++k > (1 << 26)) break;
  }
}

// HSRC: 0 = BIG top boundary (band 0), 1 = LDS Hb (fine-grained), 2 = global HX
//       (chunk-granular, staged through HScr).
// HDST: 0 = LDS Hb + fine counter, 1 = global HX + chunk flag, 2 = none (band 15).
template<int HSRC, int HDST>
static __device__ __forceinline__ void run_band(
    const ushort_t* __restrict__ xbB, const ushort_t* __restrict__ ybB,
    const float* __restrict__ x2B, const float* __restrict__ y2B,
    const float* __restrict__ HXin, float* __restrict__ HXout,
    int* __restrict__ fGin, int* __restrict__ fGout,
    ushort_t* __restrict__ Dtw, const float* __restrict__ HbSrc,
    float* __restrict__ HbDst, float* __restrict__ HScr,
    int* __restrict__ cin, int* __restrict__ cout,
    const int lane, const int W, float* __restrict__ outp)
{
  const int m = lane & 15, q = lane >> 4, l7 = lane & 7;
  const int i0 = W * 64;

  short8 af[4][2];
  #pragma unroll
  for (int mt = 0; mt < 4; ++mt)
    #pragma unroll
    for (int ks = 0; ks < 2; ++ks)
      af[mt][ks] = *(const short8*)(xbB + (size_t)(i0 + mt * 16 + m) * C_ + ks * 32 + q * 8);
  f32x4 x2q[4];
  #pragma unroll
  for (int mt = 0; mt < 4; ++mt) x2q[mt] = *(const f32x4*)(x2B + i0 + mt * 16 + q * 4);

  short8 bfr0[4], bfr1[4];
  f32x4 y2r = {0.f, 0.f, 0.f, 0.f};
  auto load_bfr = [&](int tc) {
    const ushort_t* yb0 = ybB + (size_t)tc * 64 * C_;
    #pragma unroll
    for (int nt = 0; nt < 4; ++nt) {
      bfr0[nt] = *(const short8*)(yb0 + (size_t)(nt * 16 + m) * C_ + q * 8);
      bfr1[nt] = *(const short8*)(yb0 + (size_t)(nt * 16 + m) * C_ + 32 + q * 8);
      y2r[nt] = y2B[tc * 64 + nt * 16 + m];
    }
  };

  // One (mt,nt) gram pair: 2 MFMA + epilogue -> skewed LDS slot (col+row)&127.
  auto gram_pair = [&](auto PC, const int gcb) {
    constexpr int p = decltype(PC)::v;
    constexpr int mt = p >> 2;
    constexpr int nt = p & 3;
    f32x4 acc = {0.f, 0.f, 0.f, 0.f};
    acc = __builtin_amdgcn_mfma_f32_16x16x32_bf16(af[mt][0], bfr0[nt], acc, 0, 0, 0);
    acc = __builtin_amdgcn_mfma_f32_16x16x32_bf16(af[mt][1], bfr1[nt], acc, 0, 0, 0);
    const float y2v = y2r[nt];
    float d0 = fmaf(acc[0], -2.f * INV_LN2, x2q[mt][0] + y2v);
    float d1 = fmaf(acc[1], -2.f * INV_LN2, x2q[mt][1] + y2v);
    float d2 = fmaf(acc[2], -2.f * INV_LN2, x2q[mt][2] + y2v);
    float d3 = fmaf(acc[3], -2.f * INV_LN2, x2q[mt][3] + y2v);
    unsigned p01 = cvt_pk_bf16(d0, d1);
    unsigned p23 = cvt_pk_bf16(d2, d3);
    const int rr = mt * 16 + q * 4;
    const int cs = gcb + nt * 16 + m + rr;
    ushort_t* base = Dtw + rr * DSTR;
    base[            ( cs      & 127)] = (ushort_t)p01;
    base[    DSTR +  ((cs + 1) & 127)] = (ushort_t)(p01 >> 16);
    base[2 * DSTR +  ((cs + 2) & 127)] = (ushort_t)p23;
    base[3 * DSTR +  ((cs + 3) & 127)] = (ushort_t)(p23 >> 16);
  };

  float cur = 0.f, dgp = BIGV, hvv = BIGV;
  const float zsel = (W == 0 && lane == 0) ? 0.0f : BIGV;  // R[-1][-1]=0 at origin
  const ushort_t* DtLane = Dtw + lane * DSTR;

  // One fused chunk: 8 groups x {fine wait + hv load, D prefetch, 8 DP steps,
  // 2 gram pairs of tile t+1, counter publish}.
  auto dp_chunk = [&](auto FC, auto GC, const int t) {
    constexpr bool FIRST  = decltype(FC)::v != 0;
    constexpr bool DOGRAM = decltype(GC)::v != 0;
    const unsigned* pw = (const unsigned*)(DtLane + ((t << 6) & 127));
    const int cb = (t << 6) - 63;      // lane-63 col at local step u is cb+u
    const int gcb = (t + 1) << 6;

    if constexpr (HSRC == 2) {         // stage the chunk's 64 top values in LDS
      spin_glb(fGin, t + 1);
      HScr[lane] = HXin[(t << 6) + lane];
    }

    unsigned d0 = pw[0], d1 = pw[1], d2 = pw[2], d3 = pw[3];

    auto step = [&](unsigned dw, int k, int u) -> float {
      float dv = __builtin_bit_cast(float, (k & 1) ? (dw & 0xffff0000u) : (dw << 16));
      float up = dpp_shr1(hvv, cur);   // lane0 <- hvv[0] = current top value
      float dg = dgp, lf = cur;
      if constexpr (FIRST) {
        bool at0 = (u == lane);        // c == 0: left boundary
        dg = at0 ? zsel : dg;
        lf = at0 ? BIGV : lf;
      }
      float mn = fminf(fminf(up, dg), lf);
      float e = __builtin_amdgcn_exp2f(mn - up) + __builtin_amdgcn_exp2f(mn - dg)
              + __builtin_amdgcn_exp2f(mn - lf);
      float nv = (dv + mn) - __builtin_amdgcn_logf(e);   // v_log_f32 = log2
      dgp = up;
      if constexpr (HSRC != 0) hvv = dpp_shl1(hvv);
      if constexpr (FIRST) { if (u >= lane) cur = nv; }
      else cur = nv;
      return nv;
    };
    auto flush4 = [&](int c0, float v0, float v1, float v2, float v3) {
      if constexpr (HDST == 0) {
        if (lane == 63) { HbDst[c0] = v0; HbDst[c0+1] = v1; HbDst[c0+2] = v2; HbDst[c0+3] = v3; }
      } else if constexpr (HDST == 1) {
        if (lane == 63) { HXout[c0] = v0; HXout[c0+1] = v1; HXout[c0+2] = v2; HXout[c0+3] = v3; }
      }
    };

    sfor<0, 8>([&](auto GG) {
      constexpr int g = decltype(GG)::v;
      // fine-grained wait + 8-col top-row load (lanes 0..7 hold cols +0..7)
      if constexpr (HSRC == 1) {
        if constexpr ((g & 1) == 0) spin_lds(cin, (t << 6) + (g << 3) + 16);
        hvv = HbSrc[(t << 6) + (g << 3) + l7];
      } else if constexpr (HSRC == 2) {
        hvv = HScr[(g << 3) + l7];
      }
      unsigned n0 = 0, n1 = 0, n2 = 0, n3 = 0;
      if constexpr (g < 7) {
        n0 = pw[4*g+4]; n1 = pw[4*g+5]; n2 = pw[4*g+6]; n3 = pw[4*g+7];
      }
      const int u0 = g << 3;
      float v0 = step(d0, 0, u0 + 0);
      float v1 = step(d0, 1, u0 + 1);
      float v2 = step(d1, 0, u0 + 2);
      float v3 = step(d1, 1, u0 + 3);
      if constexpr (!FIRST) flush4(cb + u0, v0, v1, v2, v3);
      float v4 = step(d2, 0, u0 + 4);
      float v5 = step(d2, 1, u0 + 5);
      float v6 = step(d3, 0, u0 + 6);
      float v7 = step(d3, 1, u0 + 7);
      if constexpr (!FIRST) flush4(cb + u0 + 4, v4, v5, v6, v7);
      if constexpr (DOGRAM) {          // 2 of 16 gram pairs for tile t+1
        gram_pair(IC<2*g>{}, gcb);
        gram_pair(IC<2*g+1>{}, gcb);
      }
      if constexpr (HDST == 0 && !FIRST) {
        if constexpr ((g & 1) == 1) {  // publish bottom-col count (release)
          if (lane == 0)
            __hip_atomic_store(cout, (t << 6) + (g << 3) - 55,
                               __ATOMIC_RELEASE, __HIP_MEMORY_SCOPE_WORKGROUP);
        }
      }
      d0 = n0; d1 = n1; d2 = n2; d3 = n3;
      (void)v0;(void)v1;(void)v2;(void)v3;(void)v4;(void)v5;(void)v6;(void)v7;
    });
    if constexpr (FIRST) {             // chunk 0: only col 0 valid on bottom row
      if (lane == 63) {
        if constexpr (HDST == 0) HbDst[0] = cur;
        else if constexpr (HDST == 1) HXout[0] = cur;
      }
      if constexpr (HDST == 0) {
        if (lane == 0)
          __hip_atomic_store(cout, 1, __ATOMIC_RELEASE, __HIP_MEMORY_SCOPE_WORKGROUP);
      }
    }
  };

  auto signal_glb = [&](int v) {
    if constexpr (HDST == 1) {
      if (lane == 0) __hip_atomic_store(fGout, v, __ATOMIC_RELEASE, __HIP_MEMORY_SCOPE_AGENT);
    }
  };

  // Tail: 63 skew-drain steps, c = 1024 + u - lane, valid iff u < lane.
  auto dp_tail = [&]() {
    const unsigned* pw = (const unsigned*)DtLane;    // slots 0..63
    #pragma unroll 1
    for (int g = 0; g < 8; ++g) {
      unsigned w0 = pw[g*4], w1 = pw[g*4+1], w2 = pw[g*4+2], w3 = pw[g*4+3];
      #pragma unroll
      for (int k = 0; k < 8; ++k) {
        const int u = g * 8 + k;
        unsigned dw = (k < 2) ? w0 : (k < 4) ? w1 : (k < 6) ? w2 : w3;
        float dv = __builtin_bit_cast(float, (k & 1) ? (dw & 0xffff0000u) : (dw << 16));
        float up = dpp_shr1(BIGV, cur);
        float dg = dgp, lf = cur;
        float mn = fminf(fminf(up, dg), lf);
        float e = __builtin_amdgcn_exp2f(mn - up) + __builtin_amdgcn_exp2f(mn - dg)
                + __builtin_amdgcn_exp2f(mn - lf);
        float nv = (dv + mn) - __builtin_amdgcn_logf(e);
        dgp = up;
        if (u < lane) {
          cur = nv;
          if (lane == 63) {
            if constexpr (HDST == 0) HbDst[961 + u] = nv;
            else if constexpr (HDST == 1) HXout[961 + u] = nv;
          }
        }
      }
      if constexpr (HDST == 0) {       // publish tail cols per group
        if (lane == 0)
          __hip_atomic_store(cout, (g < 7) ? (969 + 8 * g) : 1024,
                             __ATOMIC_RELEASE, __HIP_MEMORY_SCOPE_WORKGROUP);
      }
    }
  };

  load_bfr(0);
  sfor<0, 16>([&](auto PC) { gram_pair(PC, 0); });   // full gram for tile 0

  load_bfr(1);
  dp_chunk(IC<1>{}, IC<1>{}, 0);
  signal_glb(0);
  #pragma unroll 1
  for (int t = 1; t <= 14; ++t) {
    load_bfr(t + 1);
    dp_chunk(IC<0>{}, IC<1>{}, t);
    signal_glb(t);
  }
  dp_chunk(IC<0>{}, IC<0>{}, 15);
  signal_glb(15);
  dp_tail();
  signal_glb(16);
  if (W == 15 && lane == 63) *outp = cur * LN2F;
}

__global__ __launch_bounds__(256) void sdtw_kernel(
    const ushort_t* __restrict__ xb, const ushort_t* __restrict__ yb,
    const float* __restrict__ x2g, const float* __restrict__ y2g,
    float* __restrict__ HXg, int* __restrict__ flagsG,
    float* __restrict__ out)
{
  // LDS: Dt 4*64*130*2 = 66560 ; Hb 3*1280*4 = 15360 ; HScr 256 ; cflag 16
  //   => 82192 B (> 80 KiB on purpose: 1 block/CU, all 256 blocks resident)
  __shared__ ushort_t Dt[4][64 * DSTR];
  __shared__ float Hb[3][HBSTR];
  __shared__ float HScr[64];
  __shared__ int cflag[4];

  const int b = blockIdx.x & 63;       // blocks b, b+64, b+128, b+192: same XCD slot
  const int sub = blockIdx.x >> 6;     // 0..3 -> bands sub*4 .. sub*4+3
  const int w = threadIdx.x >> 6;
  const int lane = threadIdx.x & 63;
  const int W = sub * 4 + w;

  if (threadIdx.x < 4) cflag[threadIdx.x] = 0;
  __syncthreads();                     // only barrier in the kernel

  const ushort_t* xbB = xb + (size_t)b * L_ * C_;
  const ushort_t* ybB = yb + (size_t)b * L_ * C_;
  const float* x2B = x2g + b * L_;
  const float* y2B = y2g + b * L_;
  // boundary buffers: HXg[b][bnd][1024], bnd = 0,1,2 after bands 3,7,11
  const float* HXin = HXg + ((size_t)b * 3 + (sub > 0 ? sub - 1 : 0)) * L_;
  float* HXout      = HXg + ((size_t)b * 3 + (sub < 3 ? sub : 2)) * L_;
  int* fGin  = flagsG + b * 3 + (sub > 0 ? sub - 1 : 0);
  int* fGout = flagsG + b * 3 + (sub < 3 ? sub : 2);
  ushort_t* Dtw = &Dt[w][0];
  const float* HbSrc = (w > 0) ? &Hb[w - 1][0] : &Hb[0][0];
  float* HbDst = (w < 3) ? &Hb[w][0] : &Hb[0][0];
  int* cin  = (w > 0) ? &cflag[w - 1] : &cflag[0];
  int* cout = (w < 3) ? &cflag[w] : &cflag[3];
  float* outp = out + b;

  if (sub == 0) {
    if (w == 0)      run_band<0, 0>(xbB, ybB, x2B, y2B, HXin, HXout, fGin, fGout, Dtw, HbSrc, HbDst, HScr, cin, cout, lane, W, outp);
    else if (w < 3)  run_band<1, 0>(xbB, ybB, x2B, y2B, HXin, HXout, fGin, fGout, Dtw, HbSrc, HbDst, HScr, cin, cout, lane, W, outp);
    else             run_band<1, 1>(xbB, ybB, x2B, y2B, HXin, HXout, fGin, fGout, Dtw, HbSrc, HbDst, HScr, cin, cout, lane, W, outp);
  } else if (sub < 3) {
    if (w == 0)      run_band<2, 0>(xbB, ybB, x2B, y2B, HXin, HXout, fGin, fGout, Dtw, HbSrc, HbDst, HScr, cin, cout, lane, W, outp);
    else if (w < 3)  run_band<1, 0>(xbB, ybB, x2B, y2B, HXin, HXout, fGin, fGout, Dtw, HbSrc, HbDst, HScr, cin, cout, lane, W, outp);
    else             run_band<1, 1>(xbB, ybB, x2B, y2B, HXin, HXout, fGin, fGout, Dtw, HbSrc, HbDst, HScr, cin, cout, lane, W, outp);
  } else {
    if (w == 0)      run_band<2, 0>(xbB, ybB, x2B, y2B, HXin, HXout, fGin, fGout, Dtw, HbSrc, HbDst, HScr, cin, cout, lane, W, outp);
    else if (w < 3)  run_band<1, 0>(xbB, ybB, x2B, y2B, HXin, HXout, fGin, fGout, Dtw, HbSrc, HbDst, HScr, cin, cout, lane, W, outp);
    else             run_band<1, 2>(xbB, ybB, x2B, y2B, HXin, HXout, fGin, fGout, Dtw, HbSrc, HbDst, HScr, cin, cout, lane, W, outp);
  }
}

extern "C" void kernel_launch(void* const* d_in, const int* in_sizes, int n_in,
                              void* d_out, int out_size, void* d_ws, size_t ws_size,
                              hipStream_t stream) {
  const float* x = (const float*)d_in[0];
  const float* y = (const float*)d_in[1];
  float* out = (float*)d_out;

  // ws: xb 8MB | yb 8MB | x2 256KB | y2 256KB | HX 768KB | flagsG 768B
  char* ws = (char*)d_ws;
  const size_t XB = (size_t)B_ * L_ * C_ * 2;
  const size_t NB = (size_t)B_ * L_ * 4;
  ushort_t* xb = (ushort_t*)ws;
  ushort_t* yb = (ushort_t*)(ws + XB);
  float* x2 = (float*)(ws + 2 * XB);
  float* y2 = (float*)(ws + 2 * XB + NB);
  float* HX = (float*)(ws + 2 * XB + 2 * NB);
  int* flagsG = (int*)(ws + 2 * XB + 2 * NB + (size_t)B_ * 3 * L_ * 4);

  prep_kernel<<<512, 256, 0, stream>>>(x, y, xb, yb, x2, y2, flagsG);
  sdtw_kernel<<<256, 256, 0, stream>>>(xb, yb, x2, y2, HX, flagsG, out);
}

// Round 9
// 370.387 us; speedup vs baseline: 1.1657x; 1.1657x over previous
//
#include <hip/hip_runtime.h>

// Soft-DTW, B=64, L=1024, C=64, gamma=1.
// R2 skeleton: 16 row-bands of 64 rows per batch; wave = band; lane = row.
// One continuous skewed sweep per wave; 4 waves/block, 4 blocks/batch
// (256 blocks = 256 CUs, 1 wave/SIMD). DP in base-2 log domain, 3-exp softmin
// (R2's exact step math -- 296us baseline).
// R9: FINE-GRAINED band handoff, chain-clean:
//  - producer publishes bottom-col counter every 8 steps (release, off-chain)
//  - consumer checks a PREFETCHED flag value (relaxed load issued one group
//    earlier; compiler-only fence, no waitcnt in chain) and PREFETCHES the
//    next group's 8 top-row values during the current group.
//  Band lag 128 -> ~80 steps; path 3007 -> ~2287 steps.
// Cross-block boundaries (bands 3->4, 7->8, 11->12): global HX + agent flag,
// chunk-granular as in R2.

typedef unsigned short ushort_t;
typedef __attribute__((ext_vector_type(8))) short short8;
typedef __attribute__((ext_vector_type(4))) float f32x4;
typedef __attribute__((ext_vector_type(4))) unsigned short ushort4v;

constexpr int B_ = 64, L_ = 1024, C_ = 64;
constexpr int DSTR = 130;    // u16 row stride (65 dwords): 2-way banks max
constexpr int HBSTR = 1280;  // Hb row stride: pads LDS > 80KiB -> 1 block/CU

#define BIGV 1e10f
#define INV_LN2 1.44269504088896340736f
#define LN2F 0.69314718055994530942f

template<int N> struct IC { static constexpr int v = N; };

static __device__ __forceinline__ ushort_t f2bf(float f) {
  unsigned u = __builtin_bit_cast(unsigned, f);
  unsigned r = (u + 0x7fffu + ((u >> 16) & 1u)) >> 16;
  return (ushort_t)r;
}
static __device__ __forceinline__ unsigned cvt_pk_bf16(float lo, float hi) {
  unsigned r; asm("v_cvt_pk_bf16_f32 %0, %1, %2" : "=v"(r) : "v"(lo), "v"(hi)); return r;
}
// lane i <- lane i-1; lane 0 <- old[0]   (wave_shr:1)
static __device__ __forceinline__ float dpp_shr1(float old, float src) {
  return __builtin_bit_cast(float, __builtin_amdgcn_update_dpp(
      __builtin_bit_cast(int, old), __builtin_bit_cast(int, src), 0x138, 0xF, 0xF, false));
}
// lane i <- lane i+1 (wave_shl:1, lane 63 keeps old)
static __device__ __forceinline__ float dpp_shl1(float v) {
  return __builtin_bit_cast(float, __builtin_amdgcn_update_dpp(
      __builtin_bit_cast(int, v), __builtin_bit_cast(int, v), 0x130, 0xF, 0xF, false));
}

// Pass 1: bf16 conversion (RNE), squared norms pre-scaled by 1/ln2, zero flags.
__global__ __launch_bounds__(256) void prep_kernel(
    const float* __restrict__ x, const float* __restrict__ y,
    ushort_t* __restrict__ xb, ushort_t* __restrict__ yb,
    float* __restrict__ x2, float* __restrict__ y2, int* __restrict__ flagsG)
{
  if (blockIdx.x == 0 && threadIdx.x < 192) flagsG[threadIdx.x] = 0;
  const int lane = threadIdx.x & 63;
  const int sub = lane >> 4;
  const int cg  = lane & 15;
  const int wv = (blockIdx.x * blockDim.x + threadIdx.x) >> 6;
  const int nw = (gridDim.x * blockDim.x) >> 6;
  const int totalGroups = (2 * B_ * L_) >> 2;
  for (int g = wv; g < totalGroups; g += nw) {
    int r = g * 4 + sub;
    const float* src; ushort_t* dst; float* nrm;
    if (r < B_ * L_) { src = x; dst = xb; nrm = x2; }
    else             { r -= B_ * L_; src = y; dst = yb; nrm = y2; }
    const float4 v = *(const float4*)(src + (size_t)r * C_ + cg * 4);
    ushort4v p;
    p.x = f2bf(v.x); p.y = f2bf(v.y); p.z = f2bf(v.z); p.w = f2bf(v.w);
    *(ushort4v*)(dst + (size_t)r * C_ + cg * 4) = p;
    float s = v.x*v.x + v.y*v.y + v.z*v.z + v.w*v.w;
    s += __shfl_xor(s, 1); s += __shfl_xor(s, 2);
    s += __shfl_xor(s, 4); s += __shfl_xor(s, 8);
    if (cg == 0) nrm[r] = s * INV_LN2;
  }
}

static __device__ __forceinline__ void spin_lds(int* f, int v) {
  int k = 0;
  while (__hip_atomic_load(f, __ATOMIC_ACQUIRE, __HIP_MEMORY_SCOPE_WORKGROUP) < v) {
    __builtin_amdgcn_s_sleep(1);
    if (++k > (1 << 26)) break;
  }
}
static __device__ __forceinline__ void spin_glb(int* f, int v) {
  int k = 0;
  while (__hip_atomic_load(f, __ATOMIC_ACQUIRE, __HIP_MEMORY_SCOPE_AGENT) < v) {
    __builtin_amdgcn_s_sleep(2);
    if (++k > (1 << 26)) break;
  }
}

// HSRC: 0 = BIG top boundary (band 0), 1 = LDS Hb (fine-grained prefetch),
//       2 = global HX (chunk-granular).
// HDST: 0 = LDS Hb + 8-step counter, 1 = global HX + chunk flag, 2 = none.
template<int HSRC, int HDST>
static __device__ __forceinline__ void run_band(
    const ushort_t* __restrict__ xbB, const ushort_t* __restrict__ ybB,
    const float* __restrict__ x2B, const float* __restrict__ y2B,
    const float* __restrict__ HXin, float* __restrict__ HXout,
    int* __restrict__ fGin, int* __restrict__ fGout,
    ushort_t* __restrict__ Dtw, const float* __restrict__ HbSrc,
    float* __restrict__ HbDst, int* __restrict__ cin, int* __restrict__ cout,
    const int lane, const int W, float* __restrict__ outp)
{
  const int m = lane & 15, q = lane >> 4, l7 = lane & 7;
  const int i0 = W * 64;

  short8 af[4][2];
  #pragma unroll
  for (int mt = 0; mt < 4; ++mt)
    #pragma unroll
    for (int ks = 0; ks < 2; ++ks)
      af[mt][ks] = *(const short8*)(xbB + (size_t)(i0 + mt * 16 + m) * C_ + ks * 32 + q * 8);
  f32x4 x2q[4];
  #pragma unroll
  for (int mt = 0; mt < 4; ++mt) x2q[mt] = *(const f32x4*)(x2B + i0 + mt * 16 + q * 4);

  short8 bfr0[4], bfr1[4];
  auto load_bfr = [&](int tc) {
    const ushort_t* yb0 = ybB + (size_t)tc * 64 * C_;
    #pragma unroll
    for (int nt = 0; nt < 4; ++nt) {
      bfr0[nt] = *(const short8*)(yb0 + (size_t)(nt * 16 + m) * C_ + q * 8);
      bfr1[nt] = *(const short8*)(yb0 + (size_t)(nt * 16 + m) * C_ + 32 + q * 8);
    }
  };
  // Gram tile -> skewed LDS: D[r][c] at row r, slot (c+r)&127 (base-2 scaled bf16)
  auto gram = [&](int tc) {
    const int cb = tc * 64;
    const float* y2j = y2B + cb;
    #pragma unroll
    for (int mt = 0; mt < 4; ++mt) {
      const int r0 = mt * 16 + q * 4;
      #pragma unroll
      for (int nt = 0; nt < 4; ++nt) {
        f32x4 acc = {0.f, 0.f, 0.f, 0.f};
        acc = __builtin_amdgcn_mfma_f32_16x16x32_bf16(af[mt][0], bfr0[nt], acc, 0, 0, 0);
        acc = __builtin_amdgcn_mfma_f32_16x16x32_bf16(af[mt][1], bfr1[nt], acc, 0, 0, 0);
        float y2v = y2j[nt * 16 + m];
        float d0 = fmaf(acc[0], -2.f * INV_LN2, x2q[mt][0] + y2v);
        float d1 = fmaf(acc[1], -2.f * INV_LN2, x2q[mt][1] + y2v);
        float d2 = fmaf(acc[2], -2.f * INV_LN2, x2q[mt][2] + y2v);
        float d3 = fmaf(acc[3], -2.f * INV_LN2, x2q[mt][3] + y2v);
        unsigned p01 = cvt_pk_bf16(d0, d1);
        unsigned p23 = cvt_pk_bf16(d2, d3);
        const int cs = cb + nt * 16 + m + r0;      // col + row for reg 0
        ushort_t* base = Dtw + r0 * DSTR;
        base[             ( cs      & 127)] = (ushort_t)p01;
        base[    DSTR  +  ((cs + 1) & 127)] = (ushort_t)(p01 >> 16);
        base[2 * DSTR  +  ((cs + 2) & 127)] = (ushort_t)p23;
        base[3 * DSTR  +  ((cs + 3) & 127)] = (ushort_t)(p23 >> 16);
      }
    }
  };

  float cur = 0.f, dgp = BIGV;
  float hvvC = BIGV, hvvN = BIGV;
  int fseen = 0;
  const float zsel = (W == 0 && lane == 0) ? 0.0f : BIGV;  // R[-1][-1]=0 at origin
  const ushort_t* DtLane = Dtw + lane * DSTR;

  load_bfr(0);
  gram(0);

  if constexpr (HSRC == 1) {
    spin_lds(cin, 16);                 // coverage for groups 0 and 1
    hvvC = HbSrc[l7];                  // cols 0..7 (lanes 0..7; rest junk)
    fseen = __hip_atomic_load(cin, __ATOMIC_RELAXED, __HIP_MEMORY_SCOPE_WORKGROUP);
  }

  // One 64-step chunk. FIRST = chunk 0 (left-boundary gating).
  auto dp_chunk = [&](auto FC, const int t) {
    constexpr bool FIRST = decltype(FC)::v != 0;
    const unsigned* pw = (const unsigned*)(DtLane + ((t << 6) & 127));
    const int cb = (t << 6) - 63;      // lane-63 col for local step u is cb+u

    if constexpr (HSRC == 2) {         // chunk-granular global boundary
      spin_glb(fGin, t + 1);
      hvvC = HXin[(t << 6) + lane];
    }
    unsigned a0 = pw[0], a1 = pw[1], b0 = pw[2], b1 = pw[3];

    auto step = [&](unsigned dw, int k, int u) -> float {
      float dv = __builtin_bit_cast(float, (k & 1) ? (dw & 0xffff0000u) : (dw << 16));
      float up = dpp_shr1(hvvC, cur);  // lane0 <- hvvC[0] = current top value
      float dg = dgp, lf = cur;
      if constexpr (FIRST) {
        bool at0 = (u == lane);        // c == 0: left boundary
        dg = at0 ? zsel : dg;
        lf = at0 ? BIGV : lf;
      }
      float mn = fminf(fminf(up, dg), lf);
      float e = __builtin_amdgcn_exp2f(mn - up) + __builtin_amdgcn_exp2f(mn - dg)
              + __builtin_amdgcn_exp2f(mn - lf);
      float nv = (dv + mn) - __builtin_amdgcn_logf(e);   // v_log_f32 = log2
      dgp = up;
      if constexpr (HSRC != 0) hvvC = dpp_shl1(hvvC);    // advance toward lane 0
      if constexpr (FIRST) { if (u >= lane) cur = nv; }
      else cur = nv;
      return nv;
    };
    auto flush4 = [&](int c0, float v0, float v1, float v2, float v3) {
      if constexpr (HDST == 0) {
        if (lane == 63) { HbDst[c0] = v0; HbDst[c0+1] = v1; HbDst[c0+2] = v2; HbDst[c0+3] = v3; }
      } else if constexpr (HDST == 1) {
        if (lane == 63) { HXout[c0] = v0; HXout[c0+1] = v1; HXout[c0+2] = v2; HXout[c0+3] = v3; }
      }
    };

    #pragma unroll 1
    for (int g = 0; g < 8; ++g) {
      const int u0 = g * 8;
      const int s0 = (t << 6) + u0;
      if constexpr (HSRC == 1) {
        // coverage check for NEXT group's cols (prefetched flag; usually passes)
        const int need = (s0 + 16 < 1024) ? (s0 + 16) : 1024;
        if (fseen < need) { spin_lds(cin, need); fseen = need; }
        asm volatile("" ::: "memory"); // compiler fence: no hoist of hv load
        int ha = s0 + 8 + l7; if (ha > 1023) ha = 1023;
        hvvN = HbSrc[ha];              // prefetch next group's 8 top values
        fseen = __hip_atomic_load(cin, __ATOMIC_RELAXED, __HIP_MEMORY_SCOPE_WORKGROUP);
      }
      unsigned n0 = 0, n1 = 0, n2 = 0, n3 = 0;
      if (g < 7) {
        n0 = pw[u0/2 + 4]; n1 = pw[u0/2 + 5]; n2 = pw[u0/2 + 6]; n3 = pw[u0/2 + 7];
      }
      float v0 = step(a0, 0, u0 + 0);
      float v1 = step(a0, 1, u0 + 1);
      float v2 = step(a1, 0, u0 + 2);
      float v3 = step(a1, 1, u0 + 3);
      if constexpr (!FIRST) flush4(cb + u0, v0, v1, v2, v3);
      float v4 = step(b0, 0, u0 + 4);
      float v5 = step(b0, 1, u0 + 5);
      float v6 = step(b1, 0, u0 + 6);
      float v7 = step(b1, 1, u0 + 7);
      if constexpr (!FIRST) flush4(cb + u0 + 4, v4, v5, v6, v7);
      if constexpr (HDST == 0 && !FIRST) {
        // bottom cols done through cb+u0+7 -> count = s0 - 55 (release)
        if (lane == 0)
          __hip_atomic_store(cout, s0 - 55, __ATOMIC_RELEASE, __HIP_MEMORY_SCOPE_WORKGROUP);
      }
      if constexpr (HSRC == 1) hvvC = hvvN;
      a0 = n0; a1 = n1; b0 = n2; b1 = n3;
      (void)v0; (void)v1; (void)v2; (void)v3; (void)v4; (void)v5; (void)v6; (void)v7;
    }
    if constexpr (FIRST) {
      // chunk 0: lane 63's only valid col is 0 (reached at u=63, value in cur)
      if (lane == 63) {
        if constexpr (HDST == 0) HbDst[0] = cur;
        else if constexpr (HDST == 1) HXout[0] = cur;
      }
      if constexpr (HDST == 0) {
        if (lane == 0)
          __hip_atomic_store(cout, 1, __ATOMIC_RELEASE, __HIP_MEMORY_SCOPE_WORKGROUP);
      }
    }
  };

  auto signal_glb = [&](int v) {
    if constexpr (HDST == 1) {
      if (lane == 0) __hip_atomic_store(fGout, v, __ATOMIC_RELEASE, __HIP_MEMORY_SCOPE_AGENT);
    }
  };

  // Tail: 63 skew-drain steps, c = 1024 + u - lane, valid iff u < lane.
  auto dp_tail = [&]() {
    const unsigned* pw = (const unsigned*)DtLane;    // slots 0..63
    #pragma unroll 1
    for (int g = 0; g < 8; ++g) {
      unsigned w0 = pw[g*4], w1 = pw[g*4+1], w2 = pw[g*4+2], w3 = pw[g*4+3];
      #pragma unroll
      for (int k = 0; k < 8; ++k) {
        const int u = g * 8 + k;
        unsigned dw = (k < 2) ? w0 : (k < 4) ? w1 : (k < 6) ? w2 : w3;
        float dv = __builtin_bit_cast(float, (k & 1) ? (dw & 0xffff0000u) : (dw << 16));
        float up = dpp_shr1(BIGV, cur);
        float dg = dgp, lf = cur;
        float mn = fminf(fminf(up, dg), lf);
        float e = __builtin_amdgcn_exp2f(mn - up) + __builtin_amdgcn_exp2f(mn - dg)
                + __builtin_amdgcn_exp2f(mn - lf);
        float nv = (dv + mn) - __builtin_amdgcn_logf(e);
        dgp = up;
        if (u < lane) {
          cur = nv;
          if (lane == 63) {
            if constexpr (HDST == 0) HbDst[961 + u] = nv;
            else if constexpr (HDST == 1) HXout[961 + u] = nv;
          }
        }
      }
      if constexpr (HDST == 0) {       // bottom cols through 968+8g done
        if (lane == 0)
          __hip_atomic_store(cout, (g < 7) ? (969 + 8 * g) : 1024,
                             __ATOMIC_RELEASE, __HIP_MEMORY_SCOPE_WORKGROUP);
      }
    }
  };

  load_bfr(1);
  dp_chunk(IC<1>{}, 0);
  signal_glb(0);
  gram(1);
  #pragma unroll 1
  for (int t = 1; t < 16; ++t) {
    if (t < 15) load_bfr(t + 1);
    dp_chunk(IC<0>{}, t);
    signal_glb(t);
    if (t < 15) gram(t + 1);
  }
  dp_tail();
  signal_glb(16);
  if (W == 15 && lane == 63) *outp = cur * LN2F;
}

__global__ __launch_bounds__(256) void sdtw_kernel(
    const ushort_t* __restrict__ xb, const ushort_t* __restrict__ yb,
    const float* __restrict__ x2g, const float* __restrict__ y2g,
    float* __restrict__ HXg, int* __restrict__ flagsG,
    float* __restrict__ out)
{
  // LDS: Dt 4*64*130*2 = 66560 ; Hb 3*1280*4 = 15360 ; cflag 16 => 81936 B
  // (> 80 KiB on purpose: 1 block/CU, all 256 blocks resident)
  __shared__ ushort_t Dt[4][64 * DSTR];
  __shared__ float Hb[3][HBSTR];
  __shared__ int cflag[4];

  const int b = blockIdx.x & 63;       // blocks b, b+64, b+128, b+192: same XCD slot
  const int sub = blockIdx.x >> 6;     // 0..3 -> bands sub*4 .. sub*4+3
  const int w = threadIdx.x >> 6;
  const int lane = threadIdx.x & 63;
  const int W = sub * 4 + w;

  if (threadIdx.x < 4) cflag[threadIdx.x] = 0;
  __syncthreads();                     // only barrier in the kernel

  const ushort_t* xbB = xb + (size_t)b * L_ * C_;
  const ushort_t* ybB = yb + (size_t)b * L_ * C_;
  const float* x2B = x2g + b * L_;
  const float* y2B = y2g + b * L_;
  // boundary buffers: HXg[b][bnd][1024], bnd = 0,1,2 after bands 3,7,11
  const float* HXin = HXg + ((size_t)b * 3 + (sub > 0 ? sub - 1 : 0)) * L_;
  float* HXout      = HXg + ((size_t)b * 3 + (sub < 3 ? sub : 2)) * L_;
  int* fGin  = flagsG + b * 3 + (sub > 0 ? sub - 1 : 0);
  int* fGout = flagsG + b * 3 + (sub < 3 ? sub : 2);
  ushort_t* Dtw = &Dt[w][0];
  const float* HbSrc = (w > 0) ? &Hb[w - 1][0] : &Hb[0][0];
  float* HbDst = (w < 3) ? &Hb[w][0] : &Hb[0][0];
  int* cin  = (w > 0) ? &cflag[w - 1] : &cflag[0];
  int* cout = (w < 3) ? &cflag[w] : &cflag[3];
  float* outp = out + b;

  if (sub == 0) {
    if (w == 0)      run_band<0, 0>(xbB, ybB, x2B, y2B, HXin, HXout, fGin, fGout, Dtw, HbSrc, HbDst, cin, cout, lane, W, outp);
    else if (w < 3)  run_band<1, 0>(xbB, ybB, x2B, y2B, HXin, HXout, fGin, fGout, Dtw, HbSrc, HbDst, cin, cout, lane, W, outp);
    else             run_band<1, 1>(xbB, ybB, x2B, y2B, HXin, HXout, fGin, fGout, Dtw, HbSrc, HbDst, cin, cout, lane, W, outp);
  } else if (sub < 3) {
    if (w == 0)      run_band<2, 0>(xbB, ybB, x2B, y2B, HXin, HXout, fGin, fGout, Dtw, HbSrc, HbDst, cin, cout, lane, W, outp);
    else if (w < 3)  run_band<1, 0>(xbB, ybB, x2B, y2B, HXin, HXout, fGin, fGout, Dtw, HbSrc, HbDst, cin, cout, lane, W, outp);
    else             run_band<1, 1>(xbB, ybB, x2B, y2B, HXin, HXout, fGin, fGout, Dtw, HbSrc, HbDst, cin, cout, lane, W, outp);
  } else {
    if (w == 0)      run_band<2, 0>(xbB, ybB, x2B, y2B, HXin, HXout, fGin, fGout, Dtw, HbSrc, HbDst, cin, cout, lane, W, outp);
    else if (w < 3)  run_band<1, 0>(xbB, ybB, x2B, y2B, HXin, HXout, fGin, fGout, Dtw, HbSrc, HbDst, cin, cout, lane, W, outp);
    else             run_band<1, 2>(xbB, ybB, x2B, y2B, HXin, HXout, fGin, fGout, Dtw, HbSrc, HbDst, cin, cout, lane, W, outp);
  }
}

extern "C" void kernel_launch(void* const* d_in, const int* in_sizes, int n_in,
                              void* d_out, int out_size, void* d_ws, size_t ws_size,
                              hipStream_t stream) {
  const float* x = (const float*)d_in[0];
  const float* y = (const float*)d_in[1];
  float* out = (float*)d_out;

  // ws: xb 8MB | yb 8MB | x2 256KB | y2 256KB | HX 768KB | flagsG 768B
  char* ws = (char*)d_ws;
  const size_t XB = (size_t)B_ * L_ * C_ * 2;
  const size_t NB = (size_t)B_ * L_ * 4;
  ushort_t* xb = (ushort_t*)ws;
  ushort_t* yb = (ushort_t*)(ws + XB);
  float* x2 = (float*)(ws + 2 * XB);
  float* y2 = (float*)(ws + 2 * XB + NB);
  float* HX = (float*)(ws + 2 * XB + 2 * NB);
  int* flagsG = (int*)(ws + 2 * XB + 2 * NB + (size_t)B_ * 3 * L_ * 4);

  prep_kernel<<<512, 256, 0, stream>>>(x, y, xb, yb, x2, y2, flagsG);
  sdtw_kernel<<<256, 256, 0, stream>>>(xb, yb, x2, y2, HX, flagsG, out);
}